// Round 18
// baseline (132.067 us; speedup 1.0000x reference)
//
#include <hip/hip_runtime.h>
#include <hip/hip_bf16.h>

#define N_NODES 4096
#define F_DIM   512
#define KTOT    8192
#define KSPLIT  8
#define LOG2E   1.44269504f

typedef __attribute__((ext_vector_type(8))) short bf16x8;
typedef __attribute__((ext_vector_type(4))) float f32x4;

__device__ inline unsigned short f2bf(float f) {
  union { float f; unsigned u; } c; c.f = f;
  unsigned r = c.u + 0x7fffu + ((c.u >> 16) & 1u);
  return (unsigned short)(r >> 16);
}
__device__ inline float bf2f(unsigned short u) {
  union { unsigned u; float f; } c; c.u = ((unsigned)u) << 16;
  return c.f;
}

// ---- block-wide (256 thr) pair reduction: returns (s1,s2) summed, valid on t==0 ----
__device__ inline void blk_reduce2(float& s1, float& s2, float* red) {
  int t = threadIdx.x, wv = t >> 6, ln = t & 63;
#pragma unroll
  for (int off = 32; off > 0; off >>= 1) {
    s1 += __shfl_down(s1, off);
    s2 += __shfl_down(s2, off);
  }
  if (ln == 0) { red[wv] = s1; red[4 + wv] = s2; }
  __syncthreads();
  if (t == 0) {
    s1 = red[0] + red[1] + red[2] + red[3];
    s2 = red[4] + red[5] + red[6] + red[7];
  }
}

// ---- KA: fused [v = W@a halves (512 blocks)] | [wtrans transpose->bf16 (512 blocks)] ----
__global__ __launch_bounds__(256) void k_fused_vt(const float* __restrict__ W,
                                                  const float* __restrict__ a,
                                                  float* __restrict__ v1, float* __restrict__ v2,
                                                  const float* __restrict__ wtrans,
                                                  unsigned short* __restrict__ wtT) {
  __shared__ float tile[32][33];
  __shared__ float red[8];
  int t = threadIdx.x;
  if (blockIdx.x < 512) {
    int r = blockIdx.x;
    float wA = W[(size_t)r * F_DIM + t];
    float wB = W[(size_t)r * F_DIM + 256 + t];
    float s1 = wA * a[t] + wB * a[256 + t];
    float s2 = wA * a[F_DIM + t] + wB * a[F_DIM + 256 + t];
    blk_reduce2(s1, s2, red);
    if (t == 0) { v1[r] = s1; v2[r] = s2; }
  } else {
    // transpose fp32 [1024][512] -> bf16 [512][1024]; block (gx,gy): gx=cb/32, gy=rb/32
    int b = blockIdx.x - 512;
    int c0 = (b & 15) * 32, r0 = (b >> 4) * 32;
    int tx = t & 31, ty = t >> 5;
#pragma unroll
    for (int i = ty; i < 32; i += 8)
      tile[i][tx] = wtrans[(size_t)(r0 + i) * F_DIM + c0 + tx];
    __syncthreads();
#pragma unroll
    for (int i = ty; i < 32; i += 8)
      wtT[(size_t)(c0 + i) * 1024 + r0 + tx] = f2bf(tile[tx][i]);
  }
}

// ---- KB: Wh = inp @ v (pre-scaled log2e), 256 thr ----
__global__ __launch_bounds__(256) void k_compute_wh(const float* __restrict__ inp,
                                                    const float* __restrict__ v1,
                                                    const float* __restrict__ v2,
                                                    float* __restrict__ Wh1,
                                                    float* __restrict__ Wh2) {
  __shared__ float red[8];
  int i = blockIdx.x, t = threadIdx.x;
  float x1 = inp[(size_t)i * F_DIM + t];
  float x2 = inp[(size_t)i * F_DIM + 256 + t];
  float s1 = x1 * v1[t] + x2 * v1[256 + t];
  float s2 = x1 * v2[t] + x2 * v2[256 + t];
  blk_reduce2(s1, s2, red);
  if (t == 0) { Wh1[i] = s1 * LOG2E; Wh2[i] = s2 * LOG2E; }
}

// ---- KC: fused [k_p (4096 blocks)] | [k_y (512 blocks)] ----
__global__ __launch_bounds__(256) void k_fused_py(
    const float* __restrict__ adj, const float* __restrict__ Wh1,
    const float* __restrict__ Wh2, unsigned short* __restrict__ Pcat,
    const float* __restrict__ inp, const unsigned short* __restrict__ wtT,
    unsigned short* __restrict__ YT) {
  __shared__ float red[8];
  int t = threadIdx.x;
  if (blockIdx.x < 4096) {
    // ---- k_p: Pcat row = [ exp2(e)/sp | -exp2(-e)/sn ] * (adj>0) ----
    int i = blockIdx.x;
    float w1 = Wh1[i];
    int j0 = t * 16;
    const float* ar = adj + (size_t)i * N_NODES + j0;
    float4 A0 = *(const float4*)(ar);
    float4 A1 = *(const float4*)(ar + 4);
    float4 A2 = *(const float4*)(ar + 8);
    float4 A3 = *(const float4*)(ar + 12);
    float am[16] = {A0.x, A0.y, A0.z, A0.w, A1.x, A1.y, A1.z, A1.w,
                    A2.x, A2.y, A2.z, A2.w, A3.x, A3.y, A3.z, A3.w};
    float4 wv0 = *(const float4*)(Wh2 + j0);
    float4 wv1 = *(const float4*)(Wh2 + j0 + 4);
    float4 wv2 = *(const float4*)(Wh2 + j0 + 8);
    float4 wv3 = *(const float4*)(Wh2 + j0 + 12);
    float w2[16] = {wv0.x, wv0.y, wv0.z, wv0.w, wv1.x, wv1.y, wv1.z, wv1.w,
                    wv2.x, wv2.y, wv2.z, wv2.w, wv3.x, wv3.y, wv3.z, wv3.w};
    float pe[16], ne[16];
    float sp = 0.f, sn = 0.f;
#pragma unroll
    for (int r = 0; r < 16; r++) {
      float s = w1 + w2[r];
      float e = fmaxf(s, 0.2f * s);      // leaky-relu (log2 domain)
      float p = exp2f(e);
      float n = exp2f(-e);
      if (!(am[r] > 0.f)) { p = 0.f; n = 0.f; }
      pe[r] = p; ne[r] = n; sp += p; sn += n;
    }
    blk_reduce2(sp, sn, red);
    __shared__ float fac[2];
    if (t == 0) { fac[0] = 1.f / sp; fac[1] = -1.f / sn; }
    __syncthreads();
    float rp = fac[0], rn = fac[1];
    bf16x8 o;
#pragma unroll
    for (int r = 0; r < 8; r++) o[r] = (short)f2bf(pe[r] * rp);
    *(bf16x8*)(Pcat + (size_t)i * KTOT + j0) = o;
#pragma unroll
    for (int r = 0; r < 8; r++) o[r] = (short)f2bf(pe[8 + r] * rp);
    *(bf16x8*)(Pcat + (size_t)i * KTOT + j0 + 8) = o;
#pragma unroll
    for (int r = 0; r < 8; r++) o[r] = (short)f2bf(ne[r] * rn);
    *(bf16x8*)(Pcat + (size_t)i * KTOT + 4096 + j0) = o;
#pragma unroll
    for (int r = 0; r < 8; r++) o[r] = (short)f2bf(ne[8 + r] * rn);
    *(bf16x8*)(Pcat + (size_t)i * KTOT + 4096 + j0 + 8) = o;
  } else {
    // ---- k_y: YT[f][j] = (inp@wt1)[j][f], YT[f][4096+j] = (inp@wt2)[j][f] ----
    int b = blockIdx.x - 4096;
    int l = t & 63, w = t >> 6;
    int row = l & 15, kg = l >> 4;
    int jt = (b & 63) * 64 + w * 16;
    int cb = (b >> 6) * 64;
    f32x4 acc1[4] = {}, acc2[4] = {};
    const float* ap = inp + (size_t)(jt + row) * F_DIM + kg * 8;
    for (int k0 = 0; k0 < F_DIM; k0 += 32) {
      float4 f0 = *(const float4*)(ap + k0);
      float4 f1 = *(const float4*)(ap + k0 + 4);
      bf16x8 aa;
      aa[0] = (short)f2bf(f0.x); aa[1] = (short)f2bf(f0.y); aa[2] = (short)f2bf(f0.z); aa[3] = (short)f2bf(f0.w);
      aa[4] = (short)f2bf(f1.x); aa[5] = (short)f2bf(f1.y); aa[6] = (short)f2bf(f1.z); aa[7] = (short)f2bf(f1.w);
#pragma unroll
      for (int n = 0; n < 4; n++) {
        const unsigned short* bp = wtT + (size_t)(cb + n * 16 + row) * 1024 + kg * 8 + k0;
        bf16x8 b1 = *(const bf16x8*)(bp);
        bf16x8 b2 = *(const bf16x8*)(bp + F_DIM);
        acc1[n] = __builtin_amdgcn_mfma_f32_16x16x32_bf16(aa, b1, acc1[n], 0, 0, 0);
        acc2[n] = __builtin_amdgcn_mfma_f32_16x16x32_bf16(aa, b2, acc2[n], 0, 0, 0);
      }
    }
    int jb = jt + kg * 4;
#pragma unroll
    for (int n = 0; n < 4; n++) {
      int f = cb + n * 16 + row;
      ushort4 o1, o2;
      o1.x = f2bf(acc1[n][0]); o1.y = f2bf(acc1[n][1]); o1.z = f2bf(acc1[n][2]); o1.w = f2bf(acc1[n][3]);
      o2.x = f2bf(acc2[n][0]); o2.y = f2bf(acc2[n][1]); o2.z = f2bf(acc2[n][2]); o2.w = f2bf(acc2[n][3]);
      *(ushort4*)(YT + (size_t)f * KTOT + jb) = o1;
      *(ushort4*)(YT + (size_t)f * KTOT + 4096 + jb) = o2;
    }
  }
}

// ---- K6: 8-phase 256x256 BK=64 GEMM (exact R17 kernel) ----
#define GLOAD16(gp, lp) __builtin_amdgcn_global_load_lds( \
    (const __attribute__((address_space(1))) unsigned int*)(gp), \
    (__attribute__((address_space(3))) unsigned int*)(lp), 16, 0, 0)

__global__ __launch_bounds__(512, 1) void k_pv(const unsigned short* __restrict__ Pcat,
                                               const unsigned short* __restrict__ YT,
                                               unsigned short* __restrict__ part) {
  __shared__ char ldsA[65536];   // [dbuf][half][128 rows][128 B]
  __shared__ char ldsB[65536];
  int t = threadIdx.x;
  int l = t & 63, w = t >> 6;
  int la = l & 15, kg = l >> 4;
  int wr = w >> 2, wc = w & 3;                 // 2 x 4 wave grid
  int bm0 = blockIdx.x * 256, bn0 = blockIdx.y * 256;
  int z = blockIdx.z;
  size_t zoffB = (size_t)z * (KTOT / KSPLIT) * 2;

  int lgq = ((t & 7) ^ ((t >> 3) & 7)) << 4;
  const char* gPc = (const char*)Pcat + (size_t)(bm0 + (t >> 3)) * (KTOT * 2) + zoffB + lgq;
  const char* gYt = (const char*)YT  + (size_t)(bn0 + (t >> 3)) * (KTOT * 2) + zoffB + lgq;

#define STA(T, q) GLOAD16(gPc + (size_t)(q) * 64 * (KTOT * 2) + (size_t)(T) * 128, \
                          ldsA + ((T) & 1) * 32768 + ((q) >> 1) * 16384 + ((q) & 1) * 8192 + w * 1024)
#define STB(T, u) GLOAD16(gYt + (size_t)(u) * 64 * (KTOT * 2) + (size_t)(T) * 128, \
                          ldsB + ((T) & 1) * 32768 + ((u) >> 1) * 16384 + ((u) & 1) * 8192 + w * 1024)

  f32x4 acc[8][4] = {};
  bf16x8 af[4], bfr[2][4];

#define PHASE(D, RH, KS, READB, WAITC, STAGES) do { \
  const char* Ah_ = ldsA + (D) * 32768 + wr * 16384 + (RH) * 64 * 128; \
  _Pragma("unroll") for (int mi = 0; mi < 4; mi++) \
    af[mi] = *(const bf16x8*)(Ah_ + (mi * 16 + la) * 128 + ((((KS) * 4 + kg)) ^ (la & 7)) * 16); \
  if (READB) { \
    const char* Bh_ = ldsB + (D) * 32768 + (wc >> 1) * 16384; \
    _Pragma("unroll") for (int ni = 0; ni < 4; ni++) \
      bfr[KS][ni] = *(const bf16x8*)(Bh_ + ((wc & 1) * 64 + ni * 16 + la) * 128 + ((((KS) * 4 + kg)) ^ (la & 7)) * 16); \
  } \
  WAITC; \
  STAGES; \
  __builtin_amdgcn_s_barrier(); \
  __builtin_amdgcn_s_setprio(1); \
  _Pragma("unroll") for (int mi = 0; mi < 4; mi++) \
    _Pragma("unroll") for (int ni = 0; ni < 4; ni++) \
      acc[(RH) * 4 + mi][ni] = __builtin_amdgcn_mfma_f32_16x16x32_bf16(af[mi], bfr[KS][ni], acc[(RH) * 4 + mi][ni], 0, 0, 0); \
  __builtin_amdgcn_s_setprio(0); \
  __builtin_amdgcn_s_barrier(); \
} while (0)

  // prologue: T0 fully (8 units) + T1 partial {A q0,q2; B u0,u1} (4 units)
  STA(0, 0); STA(0, 1); STA(0, 2); STA(0, 3);
  STB(0, 0); STB(0, 1); STB(0, 2); STB(0, 3);
  STA(1, 0); STA(1, 2);
  STB(1, 0); STB(1, 1);
  asm volatile("s_waitcnt vmcnt(4)" ::: "memory");   // T0 landed
  __builtin_amdgcn_s_barrier();

  for (int it = 0; it < 8; ++it) {
    int T1 = 2 * it + 1, T2 = 2 * it + 2, T3 = 2 * it + 3;
    bool more = (it < 7);
    // dbuf0 = tile 2it
    PHASE(0, 0, 0, true,  {}, { STB(T1, 2); STB(T1, 3); });
    PHASE(0, 0, 1, true,  {}, { STA(T1, 1); STA(T1, 3); });
    PHASE(0, 1, 0, false, {}, { if (more) { STA(T2, 0); STA(T2, 2); } });
    PHASE(0, 1, 1, false,
          { if (more) asm volatile("s_waitcnt vmcnt(2)" ::: "memory");
            else      asm volatile("s_waitcnt vmcnt(0)" ::: "memory"); },
          { if (more) { STB(T2, 0); STB(T2, 1); } });
    // dbuf1 = tile 2it+1
    PHASE(1, 0, 0, true,  {}, { if (more) { STB(T2, 2); STB(T2, 3); } });
    PHASE(1, 0, 1, true,  {}, { if (more) { STA(T2, 1); STA(T2, 3); } });
    PHASE(1, 1, 0, false, {}, { if (more) { STA(T3, 0); STA(T3, 2); } });
    PHASE(1, 1, 1, false,
          { if (more) asm volatile("s_waitcnt vmcnt(2)" ::: "memory");
            else      asm volatile("s_waitcnt vmcnt(0)" ::: "memory"); },
          { if (more) { STB(T3, 0); STB(T3, 1); } });
  }

  unsigned short* po = part + (size_t)z * (N_NODES * F_DIM);
#pragma unroll
  for (int rh = 0; rh < 2; rh++)
#pragma unroll
    for (int mi = 0; mi < 4; mi++)
#pragma unroll
      for (int ni = 0; ni < 4; ni++)
#pragma unroll
        for (int q = 0; q < 4; q++) {
          int i_ = bm0 + wr * 128 + rh * 64 + mi * 16 + kg * 4 + q;
          int f_ = bn0 + wc * 64 + ni * 16 + la;
          po[(size_t)i_ * F_DIM + f_] = f2bf(acc[rh * 4 + mi][ni][q]);
        }
}

// ---- K7: out = elu(sum of 8 bf16 partials), 8 elems/thread ----
__global__ __launch_bounds__(256) void k_fin(const unsigned short* __restrict__ part,
                                             float* __restrict__ out) {
  size_t idx = ((size_t)blockIdx.x * 256 + threadIdx.x) * 8;
  float s[8] = {};
#pragma unroll
  for (int p = 0; p < KSPLIT; p++) {
    bf16x8 v = *(const bf16x8*)(part + (size_t)p * (N_NODES * F_DIM) + idx);
#pragma unroll
    for (int q = 0; q < 8; q++) s[q] += bf2f((unsigned short)v[q]);
  }
#pragma unroll
  for (int q = 0; q < 8; q++) s[q] = s[q] > 0.f ? s[q] : (__expf(s[q]) - 1.f);
  float4 o0 = make_float4(s[0], s[1], s[2], s[3]);
  float4 o1 = make_float4(s[4], s[5], s[6], s[7]);
  *(float4*)(out + idx) = o0;
  *(float4*)(out + idx + 4) = o1;
}

extern "C" void kernel_launch(void* const* d_in, const int* in_sizes, int n_in,
                              void* d_out, int out_size, void* d_ws, size_t ws_size,
                              hipStream_t stream) {
  (void)in_sizes; (void)n_in; (void)out_size; (void)ws_size;
  const float* inp    = (const float*)d_in[0];   // [4096, 512]
  const float* adj    = (const float*)d_in[1];   // [4096, 4096]
  const float* W      = (const float*)d_in[2];   // [512, 512]
  const float* a      = (const float*)d_in[3];   // [1024]
  const float* wtrans = (const float*)d_in[4];   // [1024, 512]
  float* out = (float*)d_out;                    // [4096, 512]

  char* ws = (char*)d_ws;
  float* v1  = (float*)ws;             // 2KB
  float* v2  = (float*)(ws + 2048);
  float* Wh1 = (float*)(ws + 4096);    // 16KB (log2-scaled)
  float* Wh2 = (float*)(ws + 20480);

  const size_t PSZ = (size_t)N_NODES * F_DIM * 2;   // 4 MB per bf16 partial
  char* regA = ws + 65536;
  unsigned short* wtT  = (unsigned short*)regA;                    // 1MB (setup; aliased by part)
  unsigned short* part = (unsigned short*)regA;                    // 8 * 4MB = 32MB
  unsigned short* YT   = (unsigned short*)(regA + KSPLIT * PSZ);               // 8MB
  unsigned short* Pcat = (unsigned short*)(regA + KSPLIT * PSZ + 8388608);     // 64MB (linear)
  // total ~104MB

  k_fused_vt<<<1024, 256, 0, stream>>>(W, a, v1, v2, wtrans, wtT);
  k_compute_wh<<<4096, 256, 0, stream>>>(inp, v1, v2, Wh1, Wh2);
  k_fused_py<<<4096 + 512, 256, 0, stream>>>(adj, Wh1, Wh2, Pcat, inp, wtT, YT);
  k_pv<<<dim3(16, 2, KSPLIT), 512, 0, stream>>>(Pcat, YT, part);
  k_fin<<<1024, 256, 0, stream>>>(part, out);
}

// Round 19
// 119.304 us; speedup vs baseline: 1.1070x; 1.1070x over previous
//
#include <hip/hip_runtime.h>
#include <hip/hip_bf16.h>

#define N_NODES 4096
#define F_DIM   512
#define KTOT    8192
#define KSPLIT  8
#define LOG2E   1.44269504f

typedef __attribute__((ext_vector_type(8))) short bf16x8;
typedef __attribute__((ext_vector_type(4))) float f32x4;

__device__ inline unsigned short f2bf(float f) {
  union { float f; unsigned u; } c; c.f = f;
  unsigned r = c.u + 0x7fffu + ((c.u >> 16) & 1u);
  return (unsigned short)(r >> 16);
}
__device__ inline float bf2f(unsigned short u) {
  union { unsigned u; float f; } c; c.u = ((unsigned)u) << 16;
  return c.f;
}

// ---- block-wide (256 thr) pair reduction; result valid on t==0 ----
__device__ inline void blk_reduce2(float& s1, float& s2, float* red) {
  int t = threadIdx.x, wv = t >> 6, ln = t & 63;
#pragma unroll
  for (int off = 32; off > 0; off >>= 1) {
    s1 += __shfl_down(s1, off);
    s2 += __shfl_down(s2, off);
  }
  if (ln == 0) { red[wv] = s1; red[4 + wv] = s2; }
  __syncthreads();
  if (t == 0) {
    s1 = red[0] + red[1] + red[2] + red[3];
    s2 = red[4] + red[5] + red[6] + red[7];
  }
}

// ---- KA: fused [v = W@a halves (512 blocks)] | [wtrans transpose->bf16 (512 blocks)] ----
__global__ __launch_bounds__(256) void k_fused_vt(const float* __restrict__ W,
                                                  const float* __restrict__ a,
                                                  float* __restrict__ v1, float* __restrict__ v2,
                                                  const float* __restrict__ wtrans,
                                                  unsigned short* __restrict__ wtT) {
  __shared__ float tile[32][33];
  __shared__ float red[8];
  int t = threadIdx.x;
  if (blockIdx.x < 512) {
    int r = blockIdx.x;
    float wA = W[(size_t)r * F_DIM + t];
    float wB = W[(size_t)r * F_DIM + 256 + t];
    float s1 = wA * a[t] + wB * a[256 + t];
    float s2 = wA * a[F_DIM + t] + wB * a[F_DIM + 256 + t];
    blk_reduce2(s1, s2, red);
    if (t == 0) { v1[r] = s1; v2[r] = s2; }
  } else {
    int b = blockIdx.x - 512;
    int c0 = (b & 15) * 32, r0 = (b >> 4) * 32;
    int tx = t & 31, ty = t >> 5;
#pragma unroll
    for (int i = ty; i < 32; i += 8)
      tile[i][tx] = wtrans[(size_t)(r0 + i) * F_DIM + c0 + tx];
    __syncthreads();
#pragma unroll
    for (int i = ty; i < 32; i += 8)
      wtT[(size_t)(c0 + i) * 1024 + r0 + tx] = f2bf(tile[tx][i]);
  }
}

// ---- KB: Wh = inp @ v (pre-scaled log2e) ----
__global__ __launch_bounds__(256) void k_compute_wh(const float* __restrict__ inp,
                                                    const float* __restrict__ v1,
                                                    const float* __restrict__ v2,
                                                    float* __restrict__ Wh1,
                                                    float* __restrict__ Wh2) {
  __shared__ float red[8];
  int i = blockIdx.x, t = threadIdx.x;
  float x1 = inp[(size_t)i * F_DIM + t];
  float x2 = inp[(size_t)i * F_DIM + 256 + t];
  float s1 = x1 * v1[t] + x2 * v1[256 + t];
  float s2 = x1 * v2[t] + x2 * v2[256 + t];
  blk_reduce2(s1, s2, red);
  if (t == 0) { Wh1[i] = s1 * LOG2E; Wh2[i] = s2 * LOG2E; }
}

// ---- K4: YT[512][8192]: YT[f][j] = (inp@wt1)[j][f], YT[f][4096+j] = (inp@wt2)[j][f] ----
__global__ __launch_bounds__(256) void k_y(const float* __restrict__ inp,
                                           const unsigned short* __restrict__ wtT,
                                           unsigned short* __restrict__ YT) {
  int tid = threadIdx.x, l = tid & 63, w = tid >> 6;
  int row = l & 15, kg = l >> 4;
  int jt = blockIdx.x * 64 + w * 16;
  int cb = blockIdx.y * 64;
  f32x4 acc1[4] = {}, acc2[4] = {};
  const float* ap = inp + (size_t)(jt + row) * F_DIM + kg * 8;
  for (int k0 = 0; k0 < F_DIM; k0 += 32) {
    float4 f0 = *(const float4*)(ap + k0);
    float4 f1 = *(const float4*)(ap + k0 + 4);
    bf16x8 a;
    a[0] = (short)f2bf(f0.x); a[1] = (short)f2bf(f0.y); a[2] = (short)f2bf(f0.z); a[3] = (short)f2bf(f0.w);
    a[4] = (short)f2bf(f1.x); a[5] = (short)f2bf(f1.y); a[6] = (short)f2bf(f1.z); a[7] = (short)f2bf(f1.w);
#pragma unroll
    for (int n = 0; n < 4; n++) {
      const unsigned short* bp = wtT + (size_t)(cb + n * 16 + row) * 1024 + kg * 8 + k0;
      bf16x8 b1 = *(const bf16x8*)(bp);
      bf16x8 b2 = *(const bf16x8*)(bp + F_DIM);
      acc1[n] = __builtin_amdgcn_mfma_f32_16x16x32_bf16(a, b1, acc1[n], 0, 0, 0);
      acc2[n] = __builtin_amdgcn_mfma_f32_16x16x32_bf16(a, b2, acc2[n], 0, 0, 0);
    }
  }
  int jb = jt + kg * 4;
#pragma unroll
  for (int n = 0; n < 4; n++) {
    int f = cb + n * 16 + row;
    ushort4 o1, o2;
    o1.x = f2bf(acc1[n][0]); o1.y = f2bf(acc1[n][1]); o1.z = f2bf(acc1[n][2]); o1.w = f2bf(acc1[n][3]);
    o2.x = f2bf(acc2[n][0]); o2.y = f2bf(acc2[n][1]); o2.z = f2bf(acc2[n][2]); o2.w = f2bf(acc2[n][3]);
    *(ushort4*)(YT + (size_t)f * KTOT + jb) = o1;
    *(ushort4*)(YT + (size_t)f * KTOT + 4096 + jb) = o2;
  }
}

// ---- K5: Pcat LINEAR row-major = [ exp2(e)/sp | -exp2(-e)/sn ] * (adj>0), bf16 ----
__global__ __launch_bounds__(256) void k_p(const float* __restrict__ adj,
                                           const float* __restrict__ Wh1,
                                           const float* __restrict__ Wh2,
                                           unsigned short* __restrict__ Pcat) {
  int i = blockIdx.x, t = threadIdx.x;
  float w1 = Wh1[i];
  int j0 = t * 16;
  const float* ar = adj + (size_t)i * N_NODES + j0;
  float4 A0 = *(const float4*)(ar);
  float4 A1 = *(const float4*)(ar + 4);
  float4 A2 = *(const float4*)(ar + 8);
  float4 A3 = *(const float4*)(ar + 12);
  float am[16] = {A0.x, A0.y, A0.z, A0.w, A1.x, A1.y, A1.z, A1.w,
                  A2.x, A2.y, A2.z, A2.w, A3.x, A3.y, A3.z, A3.w};
  float4 wv0 = *(const float4*)(Wh2 + j0);
  float4 wv1 = *(const float4*)(Wh2 + j0 + 4);
  float4 wv2 = *(const float4*)(Wh2 + j0 + 8);
  float4 wv3 = *(const float4*)(Wh2 + j0 + 12);
  float w2[16] = {wv0.x, wv0.y, wv0.z, wv0.w, wv1.x, wv1.y, wv1.z, wv1.w,
                  wv2.x, wv2.y, wv2.z, wv2.w, wv3.x, wv3.y, wv3.z, wv3.w};
  float pe[16], ne[16];
  float sp = 0.f, sn = 0.f;
#pragma unroll
  for (int r = 0; r < 16; r++) {
    float s = w1 + w2[r];
    float e = fmaxf(s, 0.2f * s);      // leaky-relu (log2 domain)
    float p = exp2f(e);
    float n = exp2f(-e);
    if (!(am[r] > 0.f)) { p = 0.f; n = 0.f; }
    pe[r] = p; ne[r] = n; sp += p; sn += n;
  }
#pragma unroll
  for (int off = 1; off < 64; off <<= 1) { sp += __shfl_xor(sp, off); sn += __shfl_xor(sn, off); }
  __shared__ float red[2][4];
  int wv = t >> 6, ln = t & 63;
  if (ln == 0) { red[0][wv] = sp; red[1][wv] = sn; }
  __syncthreads();
  sp = red[0][0] + red[0][1] + red[0][2] + red[0][3];
  sn = red[1][0] + red[1][1] + red[1][2] + red[1][3];
  float rp = 1.f / sp;
  float rn = -1.f / sn;
  bf16x8 o;
#pragma unroll
  for (int r = 0; r < 8; r++) o[r] = (short)f2bf(pe[r] * rp);
  *(bf16x8*)(Pcat + (size_t)i * KTOT + j0) = o;
#pragma unroll
  for (int r = 0; r < 8; r++) o[r] = (short)f2bf(pe[8 + r] * rp);
  *(bf16x8*)(Pcat + (size_t)i * KTOT + j0 + 8) = o;
#pragma unroll
  for (int r = 0; r < 8; r++) o[r] = (short)f2bf(ne[r] * rn);
  *(bf16x8*)(Pcat + (size_t)i * KTOT + 4096 + j0) = o;
#pragma unroll
  for (int r = 0; r < 8; r++) o[r] = (short)f2bf(ne[8 + r] * rn);
  *(bf16x8*)(Pcat + (size_t)i * KTOT + 4096 + j0 + 8) = o;
}

// ---- K6: 8-phase 256x256 BK=64 GEMM (exact R17 kernel, best measured) ----
#define GLOAD16(gp, lp) __builtin_amdgcn_global_load_lds( \
    (const __attribute__((address_space(1))) unsigned int*)(gp), \
    (__attribute__((address_space(3))) unsigned int*)(lp), 16, 0, 0)

__global__ __launch_bounds__(512, 1) void k_pv(const unsigned short* __restrict__ Pcat,
                                               const unsigned short* __restrict__ YT,
                                               unsigned short* __restrict__ part) {
  __shared__ char ldsA[65536];   // [dbuf][half][128 rows][128 B]
  __shared__ char ldsB[65536];
  int t = threadIdx.x;
  int l = t & 63, w = t >> 6;
  int la = l & 15, kg = l >> 4;
  int wr = w >> 2, wc = w & 3;                 // 2 x 4 wave grid
  int bm0 = blockIdx.x * 256, bn0 = blockIdx.y * 256;
  int z = blockIdx.z;
  size_t zoffB = (size_t)z * (KTOT / KSPLIT) * 2;

  int lgq = ((t & 7) ^ ((t >> 3) & 7)) << 4;
  const char* gPc = (const char*)Pcat + (size_t)(bm0 + (t >> 3)) * (KTOT * 2) + zoffB + lgq;
  const char* gYt = (const char*)YT  + (size_t)(bn0 + (t >> 3)) * (KTOT * 2) + zoffB + lgq;

#define STA(T, q) GLOAD16(gPc + (size_t)(q) * 64 * (KTOT * 2) + (size_t)(T) * 128, \
                          ldsA + ((T) & 1) * 32768 + ((q) >> 1) * 16384 + ((q) & 1) * 8192 + w * 1024)
#define STB(T, u) GLOAD16(gYt + (size_t)(u) * 64 * (KTOT * 2) + (size_t)(T) * 128, \
                          ldsB + ((T) & 1) * 32768 + ((u) >> 1) * 16384 + ((u) & 1) * 8192 + w * 1024)

  f32x4 acc[8][4] = {};
  bf16x8 af[4], bfr[2][4];

#define PHASE(D, RH, KS, READB, WAITC, STAGES) do { \
  const char* Ah_ = ldsA + (D) * 32768 + wr * 16384 + (RH) * 64 * 128; \
  _Pragma("unroll") for (int mi = 0; mi < 4; mi++) \
    af[mi] = *(const bf16x8*)(Ah_ + (mi * 16 + la) * 128 + ((((KS) * 4 + kg)) ^ (la & 7)) * 16); \
  if (READB) { \
    const char* Bh_ = ldsB + (D) * 32768 + (wc >> 1) * 16384; \
    _Pragma("unroll") for (int ni = 0; ni < 4; ni++) \
      bfr[KS][ni] = *(const bf16x8*)(Bh_ + ((wc & 1) * 64 + ni * 16 + la) * 128 + ((((KS) * 4 + kg)) ^ (la & 7)) * 16); \
  } \
  WAITC; \
  STAGES; \
  __builtin_amdgcn_s_barrier(); \
  __builtin_amdgcn_s_setprio(1); \
  _Pragma("unroll") for (int mi = 0; mi < 4; mi++) \
    _Pragma("unroll") for (int ni = 0; ni < 4; ni++) \
      acc[(RH) * 4 + mi][ni] = __builtin_amdgcn_mfma_f32_16x16x32_bf16(af[mi], bfr[KS][ni], acc[(RH) * 4 + mi][ni], 0, 0, 0); \
  __builtin_amdgcn_s_setprio(0); \
  __builtin_amdgcn_s_barrier(); \
} while (0)

  // prologue: T0 fully (8 units) + T1 partial {A q0,q2; B u0,u1} (4 units)
  STA(0, 0); STA(0, 1); STA(0, 2); STA(0, 3);
  STB(0, 0); STB(0, 1); STB(0, 2); STB(0, 3);
  STA(1, 0); STA(1, 2);
  STB(1, 0); STB(1, 1);
  asm volatile("s_waitcnt vmcnt(4)" ::: "memory");   // T0 landed
  __builtin_amdgcn_s_barrier();

  for (int it = 0; it < 8; ++it) {
    int T1 = 2 * it + 1, T2 = 2 * it + 2, T3 = 2 * it + 3;
    bool more = (it < 7);
    // dbuf0 = tile 2it
    PHASE(0, 0, 0, true,  {}, { STB(T1, 2); STB(T1, 3); });
    PHASE(0, 0, 1, true,  {}, { STA(T1, 1); STA(T1, 3); });
    PHASE(0, 1, 0, false, {}, { if (more) { STA(T2, 0); STA(T2, 2); } });
    PHASE(0, 1, 1, false,
          { if (more) asm volatile("s_waitcnt vmcnt(2)" ::: "memory");
            else      asm volatile("s_waitcnt vmcnt(0)" ::: "memory"); },
          { if (more) { STB(T2, 0); STB(T2, 1); } });
    // dbuf1 = tile 2it+1
    PHASE(1, 0, 0, true,  {}, { if (more) { STB(T2, 2); STB(T2, 3); } });
    PHASE(1, 0, 1, true,  {}, { if (more) { STA(T2, 1); STA(T2, 3); } });
    PHASE(1, 1, 0, false, {}, { if (more) { STA(T3, 0); STA(T3, 2); } });
    PHASE(1, 1, 1, false,
          { if (more) asm volatile("s_waitcnt vmcnt(2)" ::: "memory");
            else      asm volatile("s_waitcnt vmcnt(0)" ::: "memory"); },
          { if (more) { STB(T3, 0); STB(T3, 1); } });
  }

  unsigned short* po = part + (size_t)z * (N_NODES * F_DIM);
#pragma unroll
  for (int rh = 0; rh < 2; rh++)
#pragma unroll
    for (int mi = 0; mi < 4; mi++)
#pragma unroll
      for (int ni = 0; ni < 4; ni++)
#pragma unroll
        for (int q = 0; q < 4; q++) {
          int i_ = bm0 + wr * 128 + rh * 64 + mi * 16 + kg * 4 + q;
          int f_ = bn0 + wc * 64 + ni * 16 + la;
          po[(size_t)i_ * F_DIM + f_] = f2bf(acc[rh * 4 + mi][ni][q]);
        }
}

// ---- K7: out = elu(sum of 8 bf16 partials), 8 elems/thread ----
__global__ __launch_bounds__(256) void k_fin(const unsigned short* __restrict__ part,
                                             float* __restrict__ out) {
  size_t idx = ((size_t)blockIdx.x * 256 + threadIdx.x) * 8;
  float s[8] = {};
#pragma unroll
  for (int p = 0; p < KSPLIT; p++) {
    bf16x8 v = *(const bf16x8*)(part + (size_t)p * (N_NODES * F_DIM) + idx);
#pragma unroll
    for (int q = 0; q < 8; q++) s[q] += bf2f((unsigned short)v[q]);
  }
#pragma unroll
  for (int q = 0; q < 8; q++) s[q] = s[q] > 0.f ? s[q] : (__expf(s[q]) - 1.f);
  float4 o0 = make_float4(s[0], s[1], s[2], s[3]);
  float4 o1 = make_float4(s[4], s[5], s[6], s[7]);
  *(float4*)(out + idx) = o0;
  *(float4*)(out + idx + 4) = o1;
}

extern "C" void kernel_launch(void* const* d_in, const int* in_sizes, int n_in,
                              void* d_out, int out_size, void* d_ws, size_t ws_size,
                              hipStream_t stream) {
  (void)in_sizes; (void)n_in; (void)out_size; (void)ws_size;
  const float* inp    = (const float*)d_in[0];   // [4096, 512]
  const float* adj    = (const float*)d_in[1];   // [4096, 4096]
  const float* W      = (const float*)d_in[2];   // [512, 512]
  const float* a      = (const float*)d_in[3];   // [1024]
  const float* wtrans = (const float*)d_in[4];   // [1024, 512]
  float* out = (float*)d_out;                    // [4096, 512]

  char* ws = (char*)d_ws;
  float* v1  = (float*)ws;             // 2KB
  float* v2  = (float*)(ws + 2048);
  float* Wh1 = (float*)(ws + 4096);    // 16KB (log2-scaled)
  float* Wh2 = (float*)(ws + 20480);

  const size_t PSZ = (size_t)N_NODES * F_DIM * 2;   // 4 MB per bf16 partial
  char* regA = ws + 65536;
  unsigned short* wtT  = (unsigned short*)regA;                    // 1MB (setup; aliased by part)
  unsigned short* part = (unsigned short*)regA;                    // 8 * 4MB = 32MB
  unsigned short* YT   = (unsigned short*)(regA + KSPLIT * PSZ);               // 8MB
  unsigned short* Pcat = (unsigned short*)(regA + KSPLIT * PSZ + 8388608);     // 64MB (linear)
  // total ~104MB

  k_fused_vt<<<1024, 256, 0, stream>>>(W, a, v1, v2, wtrans, wtT);
  k_compute_wh<<<4096, 256, 0, stream>>>(inp, v1, v2, Wh1, Wh2);
  k_y<<<dim3(64, 8), 256, 0, stream>>>(inp, wtT, YT);
  k_p<<<4096, 256, 0, stream>>>(adj, Wh1, Wh2, Pcat);
  k_pv<<<dim3(16, 2, KSPLIT), 512, 0, stream>>>(Pcat, YT, part);
  k_fin<<<1024, 256, 0, stream>>>(part, out);
}